// Round 8
// baseline (27.679 us; speedup 1.0000x reference)
//
#include <hip/hip_runtime.h>

#define HH 128
#define WW 128
#define KK 8
#define TILE 8
#define TX (WW / TILE)        // 16
#define TY (HH / TILE)        // 16
#define NTILES (TX * TY)      // 256
#define NW 8                  // waves per block
#define NT 512                // threads per block
#define CAP 1024
#define IMAX 0x7fffffff
#define EPS 1e-3f

__device__ __forceinline__ float bcastf(float v, int lane) {
    return __int_as_float(__builtin_amdgcn_readlane(__float_as_int(v), lane));
}
__device__ __forceinline__ int bcasti(int v, int lane) {
    return __builtin_amdgcn_readlane(v, lane);
}

// conditional swap so the "lo" slot holds the lexicographic smaller (z, idx)
#define CSTEP(zh, ih, dh, zl, il, dl)                                 \
    {                                                                 \
        bool sw_ = (zh < zl) || (zh == zl && ih < il);                \
        float tz_ = sw_ ? zl : zh; int ti_ = sw_ ? il : ih;           \
        float td_ = sw_ ? dl : dh;                                    \
        zl = sw_ ? zh : zl; il = sw_ ? ih : il; dl = sw_ ? dh : dl;   \
        zh = tz_; ih = ti_; dh = td_;                                 \
    }

// full insert of (z,p,dd) into sorted 8-slot list
#define INSERT(z, p, dd)                                              \
    {                                                                 \
        z7 = z; i7 = p; d7 = dd;                                      \
        CSTEP(z7, i7, d7, z6, i6, d6);                                \
        CSTEP(z6, i6, d6, z5, i5, d5);                                \
        CSTEP(z5, i5, d5, z4, i4, d4);                                \
        CSTEP(z4, i4, d4, z3, i3, d3);                                \
        CSTEP(z3, i3, d3, z2, i2, d2s);                               \
        CSTEP(z2, i2, d2s, z1, i1, d1);                               \
        CSTEP(z1, i1, d1, z0, i0, d0);                                \
    }

// ONE kernel. One block per 8x8 tile. Phase A: 512 threads scan all points
// (4-point batched x/y/r loads), rect-filter, survivors load z and append to
// LDS. Phase B: 8 waves each top-K a slice; wave 0 merges. Selection is
// exact lexicographic (z, idx) -> LDS append order cannot change the result.
__global__ void __launch_bounds__(NT) fused_raster_kernel(
                              const float* __restrict__ pts,
                              const float* __restrict__ rad,
                              int P,
                              float* __restrict__ out) {
    int t = blockIdx.x;
    int th = t / TX, tw = t % TX;
    int tid = threadIdx.x;
    int wv = tid >> 6;            // wave id 0..7
    int lane = tid & 63;          // pixel id within tile
    int pw = lane % TILE, ph = lane / TILE;
    int w = tw * TILE + pw;
    int h = th * TILE + ph;

    __shared__ float4 scand[CAP];
    __shared__ int    sidx[CAP];
    __shared__ int    scnt;
    __shared__ float lz[NW - 1][KK][64];
    __shared__ int   li[NW - 1][KK][64];
    __shared__ float ld[NW - 1][KK][64];

    if (tid == 0) scnt = 0;
    __syncthreads();

    // tile pixel-center bounds (uniform per block). xf(w) = 1-(2w+1)/128,
    // decreasing in w; yf likewise in h.
    float xhi_c = 1.0f - (2.0f * (float)(tw * TILE) + 1.0f) * (1.0f / WW);
    float xlo_c = 1.0f - (2.0f * (float)(tw * TILE + TILE - 1) + 1.0f) * (1.0f / WW);
    float yhi_c = 1.0f - (2.0f * (float)(th * TILE) + 1.0f) * (1.0f / HH);
    float ylo_c = 1.0f - (2.0f * (float)(th * TILE + TILE - 1) + 1.0f) * (1.0f / HH);

    // ---- Phase A: rect-filter all points; z loaded only for survivors ----
    for (int base = 0; base < P; base += NT * 4) {
        int p0 = base + tid;
        int p1 = p0 + NT, p2 = p0 + 2 * NT, p3 = p0 + 3 * NT;
        bool g0 = p0 < P, g1 = p1 < P, g2 = p2 < P, g3 = p3 < P;
        // issue 12 independent loads up front (x,y,r only; z deferred)
        float x0 = g0 ? pts[3 * p0] : 2.f, y0 = g0 ? pts[3 * p0 + 1] : 2.f,
              r0 = g0 ? rad[p0] : 0.f;
        float x1 = g1 ? pts[3 * p1] : 2.f, y1 = g1 ? pts[3 * p1 + 1] : 2.f,
              r1 = g1 ? rad[p1] : 0.f;
        float x2 = g2 ? pts[3 * p2] : 2.f, y2 = g2 ? pts[3 * p2 + 1] : 2.f,
              r2v = g2 ? rad[p2] : 0.f;
        float x3 = g3 ? pts[3 * p3] : 2.f, y3 = g3 ? pts[3 * p3 + 1] : 2.f,
              r3 = g3 ? rad[p3] : 0.f;

#define CONSIDER(p, x, y, r)                                              \
        if ((r > 0.0f) &&                                                 \
            (x > xlo_c - r - EPS) && (x < xhi_c + r + EPS) &&             \
            (y > ylo_c - r - EPS) && (y < yhi_c + r + EPS)) {             \
            float z = pts[3 * (p) + 2];                                   \
            if (z >= 0.0f) {                                              \
                int slot = atomicAdd(&scnt, 1);                           \
                if (slot < CAP) {                                         \
                    scand[slot] = make_float4(x, y, z, __fmul_rn(r, r));  \
                    sidx[slot] = p;                                       \
                }                                                         \
            }                                                             \
        }

        CONSIDER(p0, x0, y0, r0)
        CONSIDER(p1, x1, y1, r1)
        CONSIDER(p2, x2, y2, r2v)
        CONSIDER(p3, x3, y3, r3)
#undef CONSIDER
    }
    __syncthreads();
    int cnt = min(scnt, CAP);

    // ---- Phase B: per-wave register top-K over a slice ----
    float z0 = INFINITY, z1 = INFINITY, z2 = INFINITY, z3 = INFINITY,
          z4 = INFINITY, z5 = INFINITY, z6 = INFINITY, z7 = INFINITY;
    int   i0 = IMAX, i1 = IMAX, i2 = IMAX, i3 = IMAX,
          i4 = IMAX, i5 = IMAX, i6 = IMAX, i7 = IMAX;
    float d0 = -1.f, d1 = -1.f, d2s = -1.f, d3 = -1.f,
          d4 = -1.f, d5 = -1.f, d6 = -1.f, d7 = -1.f;

    float xf = 1.0f - (2.0f * (float)w + 1.0f) * (1.0f / (float)WW);
    float yf = 1.0f - (2.0f * (float)h + 1.0f) * (1.0f / (float)HH);

    int S = (cnt + NW - 1) / NW;
    int s0 = wv * S;
    int s1 = min(cnt, s0 + S);

    for (int base = s0; base < s1; base += 64) {
        int n = min(64, s1 - base);
        float4 cur = make_float4(0.f, 0.f, 0.f, 0.f);
        int cpi = 0;
        if (base + lane < s1) { cur = scand[base + lane]; cpi = sidx[base + lane]; }

        for (int j = 0; j < n; ++j) {
            float x  = bcastf(cur.x, j);
            float y  = bcastf(cur.y, j);
            float z  = bcastf(cur.z, j);
            float r2 = bcastf(cur.w, j);
            int   p  = bcasti(cpi, j);
            float dx = xf - x;
            float dy = yf - y;
            // match numpy rounding exactly: mul, mul, add (no fma contraction)
            float dd = __fadd_rn(__fmul_rn(dx, dx), __fmul_rn(dy, dy));
            if (dd < r2 && ((z < z7) || (z == z7 && p < i7))) {
                INSERT(z, p, dd);
            }
        }
    }

    // waves 1..7 publish their lists; wave 0 merges
    if (wv > 0) {
        int m = wv - 1;
        lz[m][0][lane] = z0; li[m][0][lane] = i0; ld[m][0][lane] = d0;
        lz[m][1][lane] = z1; li[m][1][lane] = i1; ld[m][1][lane] = d1;
        lz[m][2][lane] = z2; li[m][2][lane] = i2; ld[m][2][lane] = d2s;
        lz[m][3][lane] = z3; li[m][3][lane] = i3; ld[m][3][lane] = d3;
        lz[m][4][lane] = z4; li[m][4][lane] = i4; ld[m][4][lane] = d4;
        lz[m][5][lane] = z5; li[m][5][lane] = i5; ld[m][5][lane] = d5;
        lz[m][6][lane] = z6; li[m][6][lane] = i6; ld[m][6][lane] = d6;
        lz[m][7][lane] = z7; li[m][7][lane] = i7; ld[m][7][lane] = d7;
    }
    __syncthreads();
    if (wv != 0) return;

#pragma unroll
    for (int m = 0; m < NW - 1; ++m) {
        for (int k = 0; k < KK; ++k) {
            float z = lz[m][k][lane];
            int   p = li[m][k][lane];
            float dd = ld[m][k][lane];
            bool ins = (z < z7) || (z == z7 && p < i7);
            // incoming list sorted ascending; once nobody inserts, rest can't
            if (!__builtin_amdgcn_ballot_w64(ins)) break;
            if (ins) INSERT(z, p, dd);
        }
    }

    int pix = h * WW + w;
    float* o_idx = out;
    float* o_z   = out + HH * WW * KK;
    float* o_d   = out + 2 * HH * WW * KK;

    bool v0 = i0 != IMAX, v1 = i1 != IMAX, v2 = i2 != IMAX, v3 = i3 != IMAX;
    bool v4 = i4 != IMAX, v5 = i5 != IMAX, v6 = i6 != IMAX, v7 = i7 != IMAX;

    float4 fi_lo = make_float4(v0 ? (float)i0 : -1.f, v1 ? (float)i1 : -1.f,
                               v2 ? (float)i2 : -1.f, v3 ? (float)i3 : -1.f);
    float4 fi_hi = make_float4(v4 ? (float)i4 : -1.f, v5 ? (float)i5 : -1.f,
                               v6 ? (float)i6 : -1.f, v7 ? (float)i7 : -1.f);
    float4 fz_lo = make_float4(v0 ? z0 : -1.f, v1 ? z1 : -1.f,
                               v2 ? z2 : -1.f, v3 ? z3 : -1.f);
    float4 fz_hi = make_float4(v4 ? z4 : -1.f, v5 ? z5 : -1.f,
                               v6 ? z6 : -1.f, v7 ? z7 : -1.f);
    float4 fd_lo = make_float4(v0 ? d0 : -1.f, v1 ? d1 : -1.f,
                               v2 ? d2s : -1.f, v3 ? d3 : -1.f);
    float4 fd_hi = make_float4(v4 ? d4 : -1.f, v5 ? d5 : -1.f,
                               v6 ? d6 : -1.f, v7 ? d7 : -1.f);

    float4* oi = (float4*)(o_idx + pix * KK);
    float4* oz = (float4*)(o_z   + pix * KK);
    float4* od = (float4*)(o_d   + pix * KK);
    oi[0] = fi_lo; oi[1] = fi_hi;
    oz[0] = fz_lo; oz[1] = fz_hi;
    od[0] = fd_lo; od[1] = fd_hi;
}

extern "C" void kernel_launch(void* const* d_in, const int* in_sizes, int n_in,
                              void* d_out, int out_size, void* d_ws, size_t ws_size,
                              hipStream_t stream) {
    const float* pts = (const float*)d_in[0];   // (P,3) f32
    const float* rad = (const float*)d_in[1];   // (P,)  f32
    int P = in_sizes[0] / 3;
    (void)d_ws; (void)ws_size;

    fused_raster_kernel<<<NTILES, NT, 0, stream>>>(pts, rad, P, (float*)d_out);
}